// Round 2
// baseline (294.464 us; speedup 1.0000x reference)
//
#include <hip/hip_runtime.h>

// VelVector: per point n (N=500000), K=32 neighbors, D=3.
//   nd[k] = normalize(neighbors[n,k]-pos[n]); w[k] = MLP(nd[k]) (3->5->5->1);
//   out[n] = normalize(sum_k nd[k]*w[k])
//
// R2 mapping: ONE THREAD PER POINT, serial over the 32 neighbors.
//  - No cross-lane reduction at all (R1 spent ~55 ops/lane-task on
//    __shfl_xor(width=32) clamping + bpermute); plain scalar accumulate.
//  - Neighbor block is 384 B contiguous per point, float4-aligned
//    (96 floats). Load as 8 chunks x 3 float4 = 4 neighbors per chunk.
//    Wave-level: 64 lanes x 384 B = 24 KB contiguous, every line consumed.
//  - MLP weights are wave-uniform -> scalar loads/SGPRs.
//  - No divergent store: each thread writes its own 3 floats.

#define K 32

__global__ __launch_bounds__(256) void velvec_kernel(
    const float* __restrict__ pos,   // [N,3]
    const float* __restrict__ nbr,   // [N,K,3]
    const float* __restrict__ W1,    // [5,3]
    const float* __restrict__ b1,    // [5]
    const float* __restrict__ W2,    // [5,5]
    const float* __restrict__ b2,    // [5]
    const float* __restrict__ W3,    // [1,5]
    const float* __restrict__ b3,    // [1]
    float* __restrict__ out,         // [N,3]
    int N)
{
    const int point = blockIdx.x * blockDim.x + threadIdx.x;
    if (point >= N) return;

    // ---- weights: uniform addresses -> scalar loads (free per-wave) ----
    float w1[5][3], bb1[5], w2[5][5], bb2[5], w3[5];
#pragma unroll
    for (int h = 0; h < 5; ++h) {
        bb1[h] = b1[h];
        bb2[h] = b2[h];
        w3[h]  = W3[h];
#pragma unroll
        for (int d = 0; d < 3; ++d) w1[h][d] = W1[h * 3 + d];
#pragma unroll
        for (int g = 0; g < 5; ++g) w2[h][g] = W2[h * 5 + g];
    }
    const float bb3 = b3[0];

    const float px = pos[point * 3 + 0];
    const float py = pos[point * 3 + 1];
    const float pz = pos[point * 3 + 2];

    // neighbor block: 96 floats, 16B-aligned (point*384 bytes)
    const float4* nb4 = (const float4*)(nbr + (size_t)point * (K * 3));

    float vx = 0.0f, vy = 0.0f, vz = 0.0f;

#pragma unroll
    for (int c = 0; c < 8; ++c) {          // 8 chunks x 4 neighbors
        const float4 f0 = nb4[c * 3 + 0];
        const float4 f1 = nb4[c * 3 + 1];
        const float4 f2 = nb4[c * 3 + 2];
        float nx[4], ny[4], nz[4];
        nx[0] = f0.x; ny[0] = f0.y; nz[0] = f0.z;
        nx[1] = f0.w; ny[1] = f1.x; nz[1] = f1.y;
        nx[2] = f1.z; ny[2] = f1.w; nz[2] = f2.x;
        nx[3] = f2.y; ny[3] = f2.z; nz[3] = f2.w;

#pragma unroll
        for (int j = 0; j < 4; ++j) {
            float dx = nx[j] - px;
            float dy = ny[j] - py;
            float dz = nz[j] - pz;
            float n2 = dx * dx + dy * dy + dz * dz;
            // semantics: v / max(sqrt(n2), 1e-12)
            float inv = (n2 > 1e-24f) ? __builtin_amdgcn_rsqf(n2) : 1e12f;
            dx *= inv; dy *= inv; dz *= inv;

            // tiny MLP: 3 -> 5 (relu) -> 5 (relu) -> 1
            float h1[5];
#pragma unroll
            for (int h = 0; h < 5; ++h) {
                float a = bb1[h];
                a = fmaf(w1[h][0], dx, a);
                a = fmaf(w1[h][1], dy, a);
                a = fmaf(w1[h][2], dz, a);
                h1[h] = fmaxf(a, 0.0f);
            }
            float h2[5];
#pragma unroll
            for (int g = 0; g < 5; ++g) {
                float a = bb2[g];
#pragma unroll
                for (int h = 0; h < 5; ++h) a = fmaf(w2[g][h], h1[h], a);
                h2[g] = fmaxf(a, 0.0f);
            }
            float w = bb3;
#pragma unroll
            for (int h = 0; h < 5; ++h) w = fmaf(w3[h], h2[h], w);

            vx = fmaf(dx, w, vx);
            vy = fmaf(dy, w, vy);
            vz = fmaf(dz, w, vz);
        }
    }

    // ---- final normalize + store ----
    float vn2  = vx * vx + vy * vy + vz * vz;
    float vinv = (vn2 > 1e-24f) ? __builtin_amdgcn_rsqf(vn2) : 1e12f;
    out[point * 3 + 0] = vx * vinv;
    out[point * 3 + 1] = vy * vinv;
    out[point * 3 + 2] = vz * vinv;
}

extern "C" void kernel_launch(void* const* d_in, const int* in_sizes, int n_in,
                              void* d_out, int out_size, void* d_ws, size_t ws_size,
                              hipStream_t stream) {
    const float* pos = (const float*)d_in[0];
    const float* nbr = (const float*)d_in[1];
    const float* W1  = (const float*)d_in[2];
    const float* b1  = (const float*)d_in[3];
    const float* W2  = (const float*)d_in[4];
    const float* b2  = (const float*)d_in[5];
    const float* W3  = (const float*)d_in[6];
    const float* b3  = (const float*)d_in[7];
    float* out = (float*)d_out;

    const int N = in_sizes[0] / 3;            // 500000
    const int threads = 256;
    const int blocks = (N + threads - 1) / threads;

    velvec_kernel<<<blocks, threads, 0, stream>>>(pos, nbr, W1, b1, W2, b2, W3, b3,
                                                  out, N);
}

// Round 3
// 289.045 us; speedup vs baseline: 1.0187x; 1.0187x over previous
//
#include <hip/hip_runtime.h>

// VelVector: per point n (N=500000), K=32 neighbors, D=3.
//   nd[k] = normalize(neighbors[n,k]-pos[n]); w[k] = MLP(nd[k]) (3->5->5->1);
//   out[n] = normalize(sum_k nd[k]*w[k])
//
// R3: canonical max-BW structure.
//  - Block = 256 threads handles 64 points. Its neighbor data is
//    64*384 B = 24 KB CONTIGUOUS. Staged to LDS with consecutive float4
//    loads (6 per thread, lane-consecutive -> textbook coalescing, the
//    same pattern as the 6.29 TB/s copy ubench).
//  - LDS layout padded to 25 float4 per point (stride 400 B) to spread
//    banks on the compute-phase ds_read_b128s.
//  - Compute: 4 lanes per point, 8 neighbors each, width-4 butterfly
//    (__shfl_xor masks 1,2) for the weighted sum; lanes sub<3 store x/y/z.
//  - MLP weights are wave-uniform -> scalar loads (free).

#define K 32
#define PTS_PER_BLOCK 64
#define F4_PER_PT 24          // 96 floats = 384 B of neighbor data per point
#define F4_STRIDE 25          // padded stride in LDS (float4 units)

__global__ __launch_bounds__(256) void velvec_kernel(
    const float* __restrict__ pos,   // [N,3]
    const float* __restrict__ nbr,   // [N,K,3]
    const float* __restrict__ W1,    // [5,3]
    const float* __restrict__ b1,    // [5]
    const float* __restrict__ W2,    // [5,5]
    const float* __restrict__ b2,    // [5]
    const float* __restrict__ W3,    // [1,5]
    const float* __restrict__ b3,    // [1]
    float* __restrict__ out,         // [N,3]
    int N)
{
    __shared__ float4 lds4[PTS_PER_BLOCK * F4_STRIDE];   // 25600 B

    const int t = threadIdx.x;

    // ---- stage this block's 24 KB of neighbor data, fully coalesced ----
    const int   pt_base     = blockIdx.x * PTS_PER_BLOCK;
    const int   pts_in_blk  = min(PTS_PER_BLOCK, N - pt_base);
    const int   valid4      = pts_in_blk * F4_PER_PT;          // <= 1536
    const long long base4   = (long long)pt_base * F4_PER_PT;
    const float4* __restrict__ nbr4 = (const float4*)nbr;

#pragma unroll
    for (int i = 0; i < 6; ++i) {
        int idx = t + i * 256;                                  // 0..1535
        if (idx < valid4) {
            unsigned pp = (unsigned)idx / F4_PER_PT;            // point in block
            unsigned e  = (unsigned)idx % F4_PER_PT;            // float4 within point
            lds4[pp * F4_STRIDE + e] = nbr4[base4 + idx];
        }
    }

    // ---- weights: uniform addresses -> scalar loads (free per-wave) ----
    float w1[5][3], bb1[5], w2[5][5], bb2[5], w3[5];
#pragma unroll
    for (int h = 0; h < 5; ++h) {
        bb1[h] = b1[h];
        bb2[h] = b2[h];
        w3[h]  = W3[h];
#pragma unroll
        for (int d = 0; d < 3; ++d) w1[h][d] = W1[h * 3 + d];
#pragma unroll
        for (int g = 0; g < 5; ++g) w2[h][g] = W2[h * 5 + g];
    }
    const float bb3 = b3[0];

    __syncthreads();

    // ---- compute: 4 lanes per point, 8 neighbors per lane ----
    const int p_local = t >> 2;          // 0..63
    const int sub     = t & 3;           // 0..3
    const int p       = pt_base + p_local;
    if (p >= N) return;                  // no barriers after this point

    const float px = pos[p * 3 + 0];
    const float py = pos[p * 3 + 1];
    const float pz = pos[p * 3 + 2];

    // this lane's 8 neighbors: floats [sub*24, sub*24+24) of the point
    float4 f[6];
#pragma unroll
    for (int j = 0; j < 6; ++j)
        f[j] = lds4[p_local * F4_STRIDE + sub * 6 + j];
    const float* a = (const float*)f;    // 24 floats = 8 (x,y,z) triplets

    float vx = 0.0f, vy = 0.0f, vz = 0.0f;

#pragma unroll
    for (int j = 0; j < 8; ++j) {
        float dx = a[j * 3 + 0] - px;
        float dy = a[j * 3 + 1] - py;
        float dz = a[j * 3 + 2] - pz;
        float n2 = dx * dx + dy * dy + dz * dz;
        // semantics: v / max(sqrt(n2), 1e-12)
        float inv = (n2 > 1e-24f) ? __builtin_amdgcn_rsqf(n2) : 1e12f;
        dx *= inv; dy *= inv; dz *= inv;

        // tiny MLP: 3 -> 5 (relu) -> 5 (relu) -> 1
        float h1[5];
#pragma unroll
        for (int h = 0; h < 5; ++h) {
            float acc = bb1[h];
            acc = fmaf(w1[h][0], dx, acc);
            acc = fmaf(w1[h][1], dy, acc);
            acc = fmaf(w1[h][2], dz, acc);
            h1[h] = fmaxf(acc, 0.0f);
        }
        float h2[5];
#pragma unroll
        for (int g = 0; g < 5; ++g) {
            float acc = bb2[g];
#pragma unroll
            for (int h = 0; h < 5; ++h) acc = fmaf(w2[g][h], h1[h], acc);
            h2[g] = fmaxf(acc, 0.0f);
        }
        float w = bb3;
#pragma unroll
        for (int h = 0; h < 5; ++h) w = fmaf(w3[h], h2[h], w);

        vx = fmaf(dx, w, vx);
        vy = fmaf(dy, w, vy);
        vz = fmaf(dz, w, vz);
    }

    // ---- reduce across the 4 lanes of this point (butterfly, width 4) ----
#pragma unroll
    for (int m = 1; m <= 2; m <<= 1) {
        vx += __shfl_xor(vx, m, 4);
        vy += __shfl_xor(vy, m, 4);
        vz += __shfl_xor(vz, m, 4);
    }

    // ---- final normalize + store (lanes sub=0,1,2 write x,y,z) ----
    float vn2  = vx * vx + vy * vy + vz * vz;
    float vinv = (vn2 > 1e-24f) ? __builtin_amdgcn_rsqf(vn2) : 1e12f;
    if (sub < 3) {
        float c = (sub == 0) ? vx : (sub == 1) ? vy : vz;
        out[p * 3 + sub] = c * vinv;
    }
}

extern "C" void kernel_launch(void* const* d_in, const int* in_sizes, int n_in,
                              void* d_out, int out_size, void* d_ws, size_t ws_size,
                              hipStream_t stream) {
    const float* pos = (const float*)d_in[0];
    const float* nbr = (const float*)d_in[1];
    const float* W1  = (const float*)d_in[2];
    const float* b1  = (const float*)d_in[3];
    const float* W2  = (const float*)d_in[4];
    const float* b2  = (const float*)d_in[5];
    const float* W3  = (const float*)d_in[6];
    const float* b3  = (const float*)d_in[7];
    float* out = (float*)d_out;

    const int N = in_sizes[0] / 3;            // 500000
    const int blocks = (N + PTS_PER_BLOCK - 1) / PTS_PER_BLOCK;

    velvec_kernel<<<blocks, 256, 0, stream>>>(pos, nbr, W1, b1, W2, b2, W3, b3,
                                              out, N);
}